// Round 1
// baseline (104.821 us; speedup 1.0000x reference)
//
#include <hip/hip_runtime.h>
#include <hip/hip_bf16.h>

// AttentionUtil: B=16, N=2048, D=64, fp32 in/out, softmax(QK^T/sqrt(D))V.
// Flash-style tiling with f16 MFMA (fp32 accumulate).

#define BATCH 16
#define SEQ   2048
#define DIM   64
#define QBLK  64   // q-rows per block (4 waves x 16)
#define KBLK  64   // keys per tile
#define STR   72   // LDS element stride for 64-wide rows (144B: 16B-aligned, bank-friendly)

typedef _Float16 hf8 __attribute__((ext_vector_type(8)));
typedef float f32x4 __attribute__((ext_vector_type(4)));

__global__ __launch_bounds__(256) void attn_fwd_kernel(
    const float* __restrict__ Qg,
    const float* __restrict__ Kg,
    const float* __restrict__ Vg,
    float* __restrict__ Og)
{
    __shared__ _Float16 Klds[KBLK * STR];      // [key][d]
    __shared__ _Float16 Vtlds[DIM * STR];      // [d][key]  (transposed V tile)
    __shared__ _Float16 Plds[4][16 * STR];     // per-wave [qrow][key]

    const int t    = threadIdx.x;
    const int lane = t & 63;
    const int wid  = t >> 6;          // wave id 0..3
    const int l15  = lane & 15;
    const int lg   = lane >> 4;       // 0..3

    const int blk = blockIdx.x;
    const int b   = blk / (SEQ / QBLK);
    const int qb  = (blk % (SEQ / QBLK)) * QBLK;

    // ---- load Q fragments (scaled), held in registers for whole K loop ----
    const float scale = 0.125f;  // 1/sqrt(64)
    hf8 qfrag[2];
    {
        const float* qrow = Qg + ((size_t)b * SEQ + qb + wid * 16 + l15) * DIM;
        #pragma unroll
        for (int c = 0; c < 2; ++c) {
            const int d0 = c * 32 + lg * 8;
            #pragma unroll
            for (int j = 0; j < 8; ++j)
                qfrag[c][j] = (_Float16)(qrow[d0 + j] * scale);
        }
    }

    f32x4 oacc[4] = {};          // 4 d-tiles of 16; rows = lg*4 + i
    float m_i[4], l_i[4];
    #pragma unroll
    for (int i = 0; i < 4; ++i) { m_i[i] = -INFINITY; l_i[i] = 0.f; }

    const float* Kbase = Kg + (size_t)b * SEQ * DIM;
    const float* Vbase = Vg + (size_t)b * SEQ * DIM;

    for (int kb = 0; kb < SEQ; kb += KBLK) {
        __syncthreads();   // previous iteration's LDS reads complete
        // ---- stage K tile (row-major) and V tile (transposed) as f16 ----
        {
            const int r0 = t >> 4;          // 0..15
            const int c4 = (t & 15) * 4;    // 0..60
            #pragma unroll
            for (int rep = 0; rep < 4; ++rep) {
                const int row = rep * 16 + r0;
                const float4 kv = *(const float4*)(Kbase + (size_t)(kb + row) * DIM + c4);
                _Float16* kd = &Klds[row * STR + c4];
                kd[0] = (_Float16)kv.x; kd[1] = (_Float16)kv.y;
                kd[2] = (_Float16)kv.z; kd[3] = (_Float16)kv.w;
                const float4 vv = *(const float4*)(Vbase + (size_t)(kb + row) * DIM + c4);
                Vtlds[(c4 + 0) * STR + row] = (_Float16)vv.x;
                Vtlds[(c4 + 1) * STR + row] = (_Float16)vv.y;
                Vtlds[(c4 + 2) * STR + row] = (_Float16)vv.z;
                Vtlds[(c4 + 3) * STR + row] = (_Float16)vv.w;
            }
        }
        __syncthreads();

        // ---- S = Q K^T : per wave 16q x 64k ----
        f32x4 s[4];
        #pragma unroll
        for (int kt = 0; kt < 4; ++kt) {
            f32x4 acc = {};
            #pragma unroll
            for (int c = 0; c < 2; ++c) {
                // B-frag: lane holds K[kt*16 + l15][c*32 + lg*8 + j]
                const hf8 bf = *(const hf8*)&Klds[(kt * 16 + l15) * STR + c * 32 + lg * 8];
                acc = __builtin_amdgcn_mfma_f32_16x16x32_f16(qfrag[c], bf, acc, 0, 0, 0);
            }
            s[kt] = acc;
        }

        // ---- online softmax (C-frag layout: row = lg*4+i, col = kt*16+l15) ----
        _Float16* P = Plds[wid];
        #pragma unroll
        for (int i = 0; i < 4; ++i) {
            float mx = fmaxf(fmaxf(s[0][i], s[1][i]), fmaxf(s[2][i], s[3][i]));
            #pragma unroll
            for (int mk = 1; mk <= 8; mk <<= 1)
                mx = fmaxf(mx, __shfl_xor(mx, mk, 64));
            const float mnew = fmaxf(m_i[i], mx);
            const float corr = __expf(m_i[i] - mnew);
            m_i[i] = mnew;

            float sum = 0.f;
            #pragma unroll
            for (int kt = 0; kt < 4; ++kt) {
                const float p = __expf(s[kt][i] - mnew);
                s[kt][i] = p;
                sum += p;
            }
            #pragma unroll
            for (int mk = 1; mk <= 8; mk <<= 1)
                sum += __shfl_xor(sum, mk, 64);
            l_i[i] = l_i[i] * corr + sum;

            #pragma unroll
            for (int dt = 0; dt < 4; ++dt)
                oacc[dt][i] *= corr;

            // write P row (f16) to per-wave LDS
            #pragma unroll
            for (int kt = 0; kt < 4; ++kt)
                P[(lg * 4 + i) * STR + kt * 16 + l15] = (_Float16)s[kt][i];
        }
        // same-wave DS ordering: make sure P writes land before A-frag reads
        asm volatile("s_waitcnt lgkmcnt(0)" ::: "memory");

        // ---- O += P V ----
        #pragma unroll
        for (int dt = 0; dt < 4; ++dt) {
            f32x4 acc = oacc[dt];
            #pragma unroll
            for (int c = 0; c < 2; ++c) {
                // A-frag: P[l15][c*32 + lg*8 + j]
                const hf8 pa = *(const hf8*)&P[l15 * STR + c * 32 + lg * 8];
                // B-frag: V[c*32 + lg*8 + j][dt*16 + l15] = Vt[dt*16+l15][c*32+lg*8+j]
                const hf8 vb = *(const hf8*)&Vtlds[(dt * 16 + l15) * STR + c * 32 + lg * 8];
                acc = __builtin_amdgcn_mfma_f32_16x16x32_f16(pa, vb, acc, 0, 0, 0);
            }
            oacc[dt] = acc;
        }
    }

    // ---- epilogue: normalize and store fp32 ----
    float* orow = Og + ((size_t)b * SEQ + qb + wid * 16) * DIM;
    #pragma unroll
    for (int dt = 0; dt < 4; ++dt) {
        #pragma unroll
        for (int i = 0; i < 4; ++i) {
            const int row = lg * 4 + i;
            orow[(size_t)row * DIM + dt * 16 + l15] = oacc[dt][i] / l_i[i];
        }
    }
}

extern "C" void kernel_launch(void* const* d_in, const int* in_sizes, int n_in,
                              void* d_out, int out_size, void* d_ws, size_t ws_size,
                              hipStream_t stream) {
    const float* Q = (const float*)d_in[0];
    const float* K = (const float*)d_in[1];
    const float* V = (const float*)d_in[2];
    float* O = (float*)d_out;
    const int nblocks = BATCH * (SEQ / QBLK);  // 512
    attn_fwd_kernel<<<dim3(nblocks), dim3(256), 0, stream>>>(Q, K, V, O);
}

// Round 2
// 94.665 us; speedup vs baseline: 1.1073x; 1.1073x over previous
//
#include <hip/hip_runtime.h>
#include <hip/hip_bf16.h>

// AttentionUtil: B=16, N=2048, D=64, fp32 in/out, softmax(QK^T/sqrt(D))V.
// Round 2: f16 preprocessing into d_ws (Q scaled, K cvt, V transposed),
// XOR-swizzled LDS (T2), async-stage split (T14), exp2-domain softmax.

#define BATCH 16
#define SEQ   2048
#define DIM   64
#define QBLK  64   // q-rows per block (4 waves x 16)
#define KBLK  64   // keys per tile

#define LOG2E 1.44269504088896340736f

typedef _Float16 hf8 __attribute__((ext_vector_type(8)));
typedef _Float16 hf4 __attribute__((ext_vector_type(4)));
typedef float f32x4 __attribute__((ext_vector_type(4)));

// ---------------------------------------------------------------------------
// Preprocess: Qh = (Q * 0.125*log2e) f16 ; Kh = K f16 ; Vth[b][d][k] = V f16
// ---------------------------------------------------------------------------
__global__ __launch_bounds__(256) void attn_preprocess(
    const float* __restrict__ Qg, const float* __restrict__ Kg,
    const float* __restrict__ Vg, _Float16* __restrict__ Qh,
    _Float16* __restrict__ Kh, _Float16* __restrict__ Vth)
{
    __shared__ float Tr[64 * 68];  // padded f32 transpose tile
    const int t = threadIdx.x;
    const int blk = blockIdx.x;

    if (blk < 2048) {
        // Q (blocks 0..1023) or K (1024..2047) convert, 2048 elems/block
        const bool isQ = blk < 1024;
        const float* src = isQ ? Qg : Kg;
        _Float16* dst = isQ ? Qh : Kh;
        const float s = isQ ? (0.125f * LOG2E) : 1.0f;
        const size_t base = (size_t)(blk & 1023) * 2048 + (size_t)t * 8;
        const float4 a = *(const float4*)(src + base);
        const float4 b = *(const float4*)(src + base + 4);
        hf8 o;
        o[0] = (_Float16)(a.x * s); o[1] = (_Float16)(a.y * s);
        o[2] = (_Float16)(a.z * s); o[3] = (_Float16)(a.w * s);
        o[4] = (_Float16)(b.x * s); o[5] = (_Float16)(b.y * s);
        o[6] = (_Float16)(b.z * s); o[7] = (_Float16)(b.w * s);
        *(hf8*)(dst + base) = o;
    } else {
        // V transpose: 512 tiles of 64k x 64d
        const int tb = blk - 2048;
        const int b  = tb >> 5;
        const int k0 = (tb & 31) * 64;
        const int r0 = t >> 4;          // 0..15
        const int c4 = (t & 15) * 4;    // 0..60
        #pragma unroll
        for (int rep = 0; rep < 4; ++rep) {
            const int kr = rep * 16 + r0;
            const float4 v = *(const float4*)(Vg + ((size_t)b * SEQ + k0 + kr) * DIM + c4);
            float* p = &Tr[kr * 68 + c4];
            p[0] = v.x; p[1] = v.y; p[2] = v.z; p[3] = v.w;
        }
        __syncthreads();
        #pragma unroll
        for (int rep = 0; rep < 4; ++rep) {
            const int d = rep * 16 + r0;
            hf4 o;
            #pragma unroll
            for (int j = 0; j < 4; ++j)
                o[j] = (_Float16)Tr[(c4 + j) * 68 + d];
            *(hf4*)(Vth + ((size_t)b * DIM + d) * SEQ + k0 + c4) = o;
        }
    }
}

// ---------------------------------------------------------------------------
// Main flash-attention kernel (f16 inputs from ws)
// LDS rows: 64 f16 = 128B, XOR-swizzle byte ^= ((row&7)<<4)
// ---------------------------------------------------------------------------
__global__ __launch_bounds__(256) void attn_fwd_f16(
    const _Float16* __restrict__ Qh,
    const _Float16* __restrict__ Kh,
    const _Float16* __restrict__ Vth,
    float* __restrict__ Og)
{
    __shared__ int4 Klds4[512];   // 8KB: K tile [64 k][64 d]
    __shared__ int4 Vlds4[512];   // 8KB: Vt tile [64 d][64 k]
    __shared__ int4 Plds4[512];   // 8KB: per-wave P [16 q][64 k]
    char* const Klds = (char*)Klds4;
    char* const Vlds = (char*)Vlds4;
    char* const Plds = (char*)Plds4;

    const int t    = threadIdx.x;
    const int lane = t & 63;
    const int wid  = t >> 6;
    const int l15  = lane & 15;
    const int lg   = lane >> 4;          // 0..3

    const int blk = blockIdx.x;
    const int b   = blk / (SEQ / QBLK);
    const int qb  = (blk % (SEQ / QBLK)) * QBLK;

    // Q fragments (already scaled to exp2 domain)
    const _Float16* qrow = Qh + ((size_t)b * SEQ + qb + wid * 16 + l15) * DIM;
    hf8 qfrag[2];
    qfrag[0] = *(const hf8*)(qrow + lg * 8);
    qfrag[1] = *(const hf8*)(qrow + 32 + lg * 8);

    f32x4 oacc[4] = {};
    float m_i[4], l_i[4];
    #pragma unroll
    for (int i = 0; i < 4; ++i) { m_i[i] = -INFINITY; l_i[i] = 0.f; }

    // staging assignment: chunk c covers row = c*32 + (t>>3), col = (t&7)*8
    const int sr = t >> 3;          // 0..31
    const int sc = (t & 7) * 8;     // elem col
    const int swz = (sr & 7) << 4;
    const int boff0 = (sr)      * 128 + ((sc * 2) ^ swz);
    const int boff1 = (32 + sr) * 128 + ((sc * 2) ^ swz);

    const _Float16* Kbase = Kh  + (size_t)b * SEQ * DIM;
    const _Float16* Vbase = Vth + (size_t)b * DIM * SEQ;

    // prefetch tile 0
    int4 pk0 = *(const int4*)(Kbase + (size_t)(sr)      * DIM + sc);
    int4 pk1 = *(const int4*)(Kbase + (size_t)(32 + sr) * DIM + sc);
    int4 pv0 = *(const int4*)(Vbase + (size_t)(sr)      * SEQ + sc);
    int4 pv1 = *(const int4*)(Vbase + (size_t)(32 + sr) * SEQ + sc);

    const int rsw = (l15 & 7) << 4;  // read swizzle (row&7 == l15&7 for all our rows)
    char* const P = Plds + wid * 2048;

    for (int kb = 0; kb < SEQ; kb += KBLK) {
        __syncthreads();   // previous tile's LDS reads done
        *(int4*)(Klds + boff0) = pk0;
        *(int4*)(Klds + boff1) = pk1;
        *(int4*)(Vlds + boff0) = pv0;
        *(int4*)(Vlds + boff1) = pv1;
        __syncthreads();
        if (kb + KBLK < SEQ) {  // issue next tile's loads; overlap with compute
            const int kn = kb + KBLK;
            pk0 = *(const int4*)(Kbase + (size_t)(kn + sr)      * DIM + sc);
            pk1 = *(const int4*)(Kbase + (size_t)(kn + 32 + sr) * DIM + sc);
            pv0 = *(const int4*)(Vbase + (size_t)(sr)      * SEQ + kn + sc);
            pv1 = *(const int4*)(Vbase + (size_t)(32 + sr) * SEQ + kn + sc);
        }

        // ---- S = Q K^T (exp2 domain) ----
        f32x4 s[4];
        #pragma unroll
        for (int kt = 0; kt < 4; ++kt) {
            f32x4 acc = {};
            #pragma unroll
            for (int c = 0; c < 2; ++c) {
                const hf8 bf = *(const hf8*)(Klds + (kt * 16 + l15) * 128 + ((c * 64 + lg * 16) ^ rsw));
                acc = __builtin_amdgcn_mfma_f32_16x16x32_f16(qfrag[c], bf, acc, 0, 0, 0);
            }
            s[kt] = acc;
        }

        // ---- online softmax (C layout: row = lg*4+i, col = kt*16+l15) ----
        #pragma unroll
        for (int i = 0; i < 4; ++i) {
            float mx = fmaxf(fmaxf(s[0][i], s[1][i]), fmaxf(s[2][i], s[3][i]));
            #pragma unroll
            for (int mk = 1; mk <= 8; mk <<= 1)
                mx = fmaxf(mx, __shfl_xor(mx, mk, 64));
            const float mnew = fmaxf(m_i[i], mx);
            const float corr = __builtin_exp2f(m_i[i] - mnew);
            m_i[i] = mnew;

            float sum = 0.f;
            #pragma unroll
            for (int kt = 0; kt < 4; ++kt) {
                const float p = __builtin_exp2f(s[kt][i] - mnew);
                s[kt][i] = p;
                sum += p;
            }
            #pragma unroll
            for (int mk = 1; mk <= 8; mk <<= 1)
                sum += __shfl_xor(sum, mk, 64);
            l_i[i] = l_i[i] * corr + sum;

            #pragma unroll
            for (int dt = 0; dt < 4; ++dt)
                oacc[dt][i] *= corr;

            const int prow = lg * 4 + i;
            const int psw = (prow & 7) << 4;
            #pragma unroll
            for (int kt = 0; kt < 4; ++kt)
                *(_Float16*)(P + prow * 128 + (((kt * 16 + l15) * 2) ^ psw)) = (_Float16)s[kt][i];
        }
        asm volatile("s_waitcnt lgkmcnt(0)" ::: "memory");

        // ---- O += P V ----
        #pragma unroll
        for (int dt = 0; dt < 4; ++dt) {
            f32x4 acc = oacc[dt];
            #pragma unroll
            for (int c = 0; c < 2; ++c) {
                const hf8 pa = *(const hf8*)(P + l15 * 128 + ((c * 64 + lg * 16) ^ rsw));
                const hf8 vb = *(const hf8*)(Vlds + (dt * 16 + l15) * 128 + ((c * 64 + lg * 16) ^ rsw));
                acc = __builtin_amdgcn_mfma_f32_16x16x32_f16(pa, vb, acc, 0, 0, 0);
            }
            oacc[dt] = acc;
        }
    }

    // ---- epilogue ----
    float* orow = Og + ((size_t)b * SEQ + qb + wid * 16) * DIM;
    float inv[4];
    #pragma unroll
    for (int i = 0; i < 4; ++i) inv[i] = 1.0f / l_i[i];
    #pragma unroll
    for (int dt = 0; dt < 4; ++dt)
        #pragma unroll
        for (int i = 0; i < 4; ++i)
            orow[(size_t)(lg * 4 + i) * DIM + dt * 16 + l15] = oacc[dt][i] * inv[i];
}

// ---------------------------------------------------------------------------
// Fallback (round-1 kernel, used only if ws is too small)
// ---------------------------------------------------------------------------
#define STR 72
__global__ __launch_bounds__(256) void attn_fwd_fallback(
    const float* __restrict__ Qg, const float* __restrict__ Kg,
    const float* __restrict__ Vg, float* __restrict__ Og)
{
    __shared__ _Float16 Klds[KBLK * STR];
    __shared__ _Float16 Vtlds[DIM * STR];
    __shared__ _Float16 Plds[4][16 * STR];

    const int t = threadIdx.x;
    const int lane = t & 63;
    const int wid = t >> 6;
    const int l15 = lane & 15;
    const int lg = lane >> 4;
    const int blk = blockIdx.x;
    const int b = blk / (SEQ / QBLK);
    const int qb = (blk % (SEQ / QBLK)) * QBLK;

    const float scale = 0.125f;
    hf8 qfrag[2];
    {
        const float* qrow = Qg + ((size_t)b * SEQ + qb + wid * 16 + l15) * DIM;
        #pragma unroll
        for (int c = 0; c < 2; ++c)
            #pragma unroll
            for (int j = 0; j < 8; ++j)
                qfrag[c][j] = (_Float16)(qrow[c * 32 + lg * 8 + j] * scale);
    }
    f32x4 oacc[4] = {};
    float m_i[4], l_i[4];
    #pragma unroll
    for (int i = 0; i < 4; ++i) { m_i[i] = -INFINITY; l_i[i] = 0.f; }
    const float* Kbase = Qg ? Kg + (size_t)b * SEQ * DIM : nullptr;
    const float* Vbase = Vg + (size_t)b * SEQ * DIM;

    for (int kb = 0; kb < SEQ; kb += KBLK) {
        __syncthreads();
        {
            const int r0 = t >> 4, c4 = (t & 15) * 4;
            #pragma unroll
            for (int rep = 0; rep < 4; ++rep) {
                const int row = rep * 16 + r0;
                const float4 kv = *(const float4*)(Kbase + (size_t)(kb + row) * DIM + c4);
                _Float16* kd = &Klds[row * STR + c4];
                kd[0] = (_Float16)kv.x; kd[1] = (_Float16)kv.y;
                kd[2] = (_Float16)kv.z; kd[3] = (_Float16)kv.w;
                const float4 vv = *(const float4*)(Vbase + (size_t)(kb + row) * DIM + c4);
                Vtlds[(c4 + 0) * STR + row] = (_Float16)vv.x;
                Vtlds[(c4 + 1) * STR + row] = (_Float16)vv.y;
                Vtlds[(c4 + 2) * STR + row] = (_Float16)vv.z;
                Vtlds[(c4 + 3) * STR + row] = (_Float16)vv.w;
            }
        }
        __syncthreads();
        f32x4 s[4];
        #pragma unroll
        for (int kt = 0; kt < 4; ++kt) {
            f32x4 acc = {};
            #pragma unroll
            for (int c = 0; c < 2; ++c) {
                const hf8 bf = *(const hf8*)&Klds[(kt * 16 + l15) * STR + c * 32 + lg * 8];
                acc = __builtin_amdgcn_mfma_f32_16x16x32_f16(qfrag[c], bf, acc, 0, 0, 0);
            }
            s[kt] = acc;
        }
        _Float16* Pw = Plds[wid];
        #pragma unroll
        for (int i = 0; i < 4; ++i) {
            float mx = fmaxf(fmaxf(s[0][i], s[1][i]), fmaxf(s[2][i], s[3][i]));
            #pragma unroll
            for (int mk = 1; mk <= 8; mk <<= 1) mx = fmaxf(mx, __shfl_xor(mx, mk, 64));
            const float mnew = fmaxf(m_i[i], mx);
            const float corr = __expf(m_i[i] - mnew);
            m_i[i] = mnew;
            float sum = 0.f;
            #pragma unroll
            for (int kt = 0; kt < 4; ++kt) {
                const float p = __expf(s[kt][i] - mnew);
                s[kt][i] = p; sum += p;
            }
            #pragma unroll
            for (int mk = 1; mk <= 8; mk <<= 1) sum += __shfl_xor(sum, mk, 64);
            l_i[i] = l_i[i] * corr + sum;
            #pragma unroll
            for (int dt = 0; dt < 4; ++dt) oacc[dt][i] *= corr;
            #pragma unroll
            for (int kt = 0; kt < 4; ++kt)
                Pw[(lg * 4 + i) * STR + kt * 16 + l15] = (_Float16)s[kt][i];
        }
        asm volatile("s_waitcnt lgkmcnt(0)" ::: "memory");
        #pragma unroll
        for (int dt = 0; dt < 4; ++dt) {
            f32x4 acc = oacc[dt];
            #pragma unroll
            for (int c = 0; c < 2; ++c) {
                const hf8 pa = *(const hf8*)&Pw[l15 * STR + c * 32 + lg * 8];
                const hf8 vb = *(const hf8*)&Vtlds[(dt * 16 + l15) * STR + c * 32 + lg * 8];
                acc = __builtin_amdgcn_mfma_f32_16x16x32_f16(pa, vb, acc, 0, 0, 0);
            }
            oacc[dt] = acc;
        }
    }
    float* orow = Og + ((size_t)b * SEQ + qb + wid * 16) * DIM;
    #pragma unroll
    for (int dt = 0; dt < 4; ++dt)
        #pragma unroll
        for (int i = 0; i < 4; ++i)
            orow[(size_t)(lg * 4 + i) * DIM + dt * 16 + l15] = oacc[dt][i] / l_i[i];
}

extern "C" void kernel_launch(void* const* d_in, const int* in_sizes, int n_in,
                              void* d_out, int out_size, void* d_ws, size_t ws_size,
                              hipStream_t stream) {
    const float* Q = (const float*)d_in[0];
    const float* K = (const float*)d_in[1];
    const float* V = (const float*)d_in[2];
    float* O = (float*)d_out;
    const size_t nelem = (size_t)BATCH * SEQ * DIM;  // 2M
    if (ws_size >= nelem * 3 * sizeof(_Float16)) {   // 12 MB
        _Float16* Qh  = (_Float16*)d_ws;
        _Float16* Kh  = Qh + nelem;
        _Float16* Vth = Kh + nelem;
        attn_preprocess<<<dim3(2560), dim3(256), 0, stream>>>(Q, K, V, Qh, Kh, Vth);
        attn_fwd_f16<<<dim3(BATCH * (SEQ / QBLK)), dim3(256), 0, stream>>>(Qh, Kh, Vth, O);
    } else {
        attn_fwd_fallback<<<dim3(BATCH * (SEQ / QBLK)), dim3(256), 0, stream>>>(Q, K, V, O);
    }
}

// Round 3
// 60.345 us; speedup vs baseline: 1.7370x; 1.5687x over previous
//
#include <hip/hip_runtime.h>
#include <hip/hip_bf16.h>

// AttentionUtil: B=16, N=2048, D=64, fp32 in/out, softmax(QK^T/sqrt(D))V.
// Round 3: 4-way K-split (occupancy) + swapped-QK^T lane-local softmax
// (T12 structure) + defer-max (T13) + vectorized P path. f16 MFMA.

#define BATCH 16
#define SEQ   2048
#define DIM   64
#define QBLK  64   // q-rows per block (4 waves x 16)
#define KBLK  64   // keys per tile
#define SPLIT 4
#define SEGLEN (SEQ / SPLIT)   // 512 keys per split

#define LOG2E 1.44269504088896340736f

typedef _Float16 hf8 __attribute__((ext_vector_type(8)));
typedef _Float16 hf4 __attribute__((ext_vector_type(4)));
typedef float f32x4 __attribute__((ext_vector_type(4)));

// ---------------------------------------------------------------------------
// Preprocess: Qh = (Q * 0.125*log2e) f16 ; Kh = K f16 ; Vth[b][d][k] = V f16
// ---------------------------------------------------------------------------
__global__ __launch_bounds__(256) void attn_preprocess(
    const float* __restrict__ Qg, const float* __restrict__ Kg,
    const float* __restrict__ Vg, _Float16* __restrict__ Qh,
    _Float16* __restrict__ Kh, _Float16* __restrict__ Vth)
{
    __shared__ float Tr[64 * 68];
    const int t = threadIdx.x;
    const int blk = blockIdx.x;

    if (blk < 2048) {
        const bool isQ = blk < 1024;
        const float* src = isQ ? Qg : Kg;
        _Float16* dst = isQ ? Qh : Kh;
        const float s = isQ ? (0.125f * LOG2E) : 1.0f;
        const size_t base = (size_t)(blk & 1023) * 2048 + (size_t)t * 8;
        const float4 a = *(const float4*)(src + base);
        const float4 b = *(const float4*)(src + base + 4);
        hf8 o;
        o[0] = (_Float16)(a.x * s); o[1] = (_Float16)(a.y * s);
        o[2] = (_Float16)(a.z * s); o[3] = (_Float16)(a.w * s);
        o[4] = (_Float16)(b.x * s); o[5] = (_Float16)(b.y * s);
        o[6] = (_Float16)(b.z * s); o[7] = (_Float16)(b.w * s);
        *(hf8*)(dst + base) = o;
    } else {
        // V transpose: 512 tiles of 64k x 64d
        const int tb = blk - 2048;
        const int b  = tb >> 5;
        const int k0 = (tb & 31) * 64;
        const int r0 = t >> 4;
        const int c4 = (t & 15) * 4;
        #pragma unroll
        for (int rep = 0; rep < 4; ++rep) {
            const int kr = rep * 16 + r0;
            const float4 v = *(const float4*)(Vg + ((size_t)b * SEQ + k0 + kr) * DIM + c4);
            float* p = &Tr[kr * 68 + c4];
            p[0] = v.x; p[1] = v.y; p[2] = v.z; p[3] = v.w;
        }
        __syncthreads();
        #pragma unroll
        for (int rep = 0; rep < 4; ++rep) {
            const int d = rep * 16 + r0;
            hf4 o;
            #pragma unroll
            for (int j = 0; j < 4; ++j)
                o[j] = (_Float16)Tr[(c4 + j) * 68 + d];
            *(hf4*)(Vth + ((size_t)b * DIM + d) * SEQ + k0 + c4) = o;
        }
    }
}

// ---------------------------------------------------------------------------
// Main: K-split flash attention, swapped-QK^T softmax.
// LDS rows 128B, XOR-swizzle byte ^= ((row&7)<<4), write+read matched.
// ---------------------------------------------------------------------------
__global__ __launch_bounds__(256) void attn_fwd_split(
    const _Float16* __restrict__ Qh, const _Float16* __restrict__ Kh,
    const _Float16* __restrict__ Vth, _Float16* __restrict__ Opart,
    float2* __restrict__ Ml)
{
    __shared__ int4 Klds4[512];   // 8KB K tile [64 k][64 d]
    __shared__ int4 Vlds4[512];   // 8KB Vt tile [64 d][64 k]
    __shared__ int4 Plds4[512];   // 8KB per-wave P [16 q][64 k]
    char* const Klds = (char*)Klds4;
    char* const Vlds = (char*)Vlds4;
    char* const Plds = (char*)Plds4;

    const int t    = threadIdx.x;
    const int lane = t & 63;
    const int wid  = t >> 6;
    const int l15  = lane & 15;
    const int lg   = lane >> 4;

    const int blk = blockIdx.x;
    const int seg = blk & (SPLIT - 1);
    const int qi  = (blk >> 2) & 31;
    const int b   = blk >> 7;
    const int qb  = qi * QBLK;
    const int k0  = seg * SEGLEN;

    const _Float16* qrow = Qh + ((size_t)b * SEQ + qb + wid * 16 + l15) * DIM;
    hf8 qfrag[2];
    qfrag[0] = *(const hf8*)(qrow + lg * 8);
    qfrag[1] = *(const hf8*)(qrow + 32 + lg * 8);

    f32x4 oacc[4] = {};
    float m = -INFINITY, l = 0.f;

    const int sr = t >> 3;          // 0..31
    const int sc = (t & 7) * 8;
    const int swz = (sr & 7) << 4;
    const int boff0 = (sr)      * 128 + ((sc * 2) ^ swz);
    const int boff1 = (32 + sr) * 128 + ((sc * 2) ^ swz);

    const _Float16* Kbase = Kh  + (size_t)b * SEQ * DIM;
    const _Float16* Vbase = Vth + (size_t)b * DIM * SEQ;

    int4 pk0 = *(const int4*)(Kbase + (size_t)(k0 + sr)      * DIM + sc);
    int4 pk1 = *(const int4*)(Kbase + (size_t)(k0 + 32 + sr) * DIM + sc);
    int4 pv0 = *(const int4*)(Vbase + (size_t)(sr)      * SEQ + k0 + sc);
    int4 pv1 = *(const int4*)(Vbase + (size_t)(32 + sr) * SEQ + k0 + sc);

    const int rsw = (l15 & 7) << 4;
    char* const P = Plds + wid * 2048;

    for (int kb = k0; kb < k0 + SEGLEN; kb += KBLK) {
        __syncthreads();
        *(int4*)(Klds + boff0) = pk0;
        *(int4*)(Klds + boff1) = pk1;
        *(int4*)(Vlds + boff0) = pv0;
        *(int4*)(Vlds + boff1) = pv1;
        __syncthreads();
        if (kb + KBLK < k0 + SEGLEN) {
            const int kn = kb + KBLK;
            pk0 = *(const int4*)(Kbase + (size_t)(kn + sr)      * DIM + sc);
            pk1 = *(const int4*)(Kbase + (size_t)(kn + 32 + sr) * DIM + sc);
            pv0 = *(const int4*)(Vbase + (size_t)(sr)      * SEQ + kn + sc);
            pv1 = *(const int4*)(Vbase + (size_t)(32 + sr) * SEQ + kn + sc);
        }

        // ---- swapped QK^T: C[row = k-in-tile, col = q] ----
        f32x4 s4[4];
        #pragma unroll
        for (int kt = 0; kt < 4; ++kt) {
            f32x4 acc = {};
            #pragma unroll
            for (int c = 0; c < 2; ++c) {
                const hf8 kf = *(const hf8*)(Klds + (kt * 16 + l15) * 128 + ((c * 64 + lg * 16) ^ rsw));
                acc = __builtin_amdgcn_mfma_f32_16x16x32_f16(kf, qfrag[c], acc, 0, 0, 0);
            }
            s4[kt] = acc;
        }
        // lane now holds S[k = kt*16 + lg*4 + r][q = l15]

        // ---- lane-local softmax over this tile's 64 keys ----
        float mx = s4[0][0];
        #pragma unroll
        for (int kt = 0; kt < 4; ++kt)
            #pragma unroll
            for (int r = 0; r < 4; ++r)
                mx = fmaxf(mx, s4[kt][r]);
        mx = fmaxf(mx, __shfl_xor(mx, 16, 64));
        mx = fmaxf(mx, __shfl_xor(mx, 32, 64));

        float corr = 1.0f;
        const bool need_rescale = !__all(mx - m <= 8.0f);  // defer-max (T13)
        if (need_rescale) {
            const float mnew = fmaxf(m, mx);
            corr = exp2f(m - mnew);
            m = mnew;
        }

        float sum = 0.f;
        #pragma unroll
        for (int kt = 0; kt < 4; ++kt)
            #pragma unroll
            for (int r = 0; r < 4; ++r) {
                const float p = exp2f(s4[kt][r] - m);
                s4[kt][r] = p;
                sum += p;
            }
        sum += __shfl_xor(sum, 16, 64);
        sum += __shfl_xor(sum, 32, 64);
        l = l * corr + sum;

        if (need_rescale) {
            #pragma unroll
            for (int i = 0; i < 4; ++i) {
                const float ci = __shfl(corr, lg * 4 + i, 64);
                #pragma unroll
                for (int dt = 0; dt < 4; ++dt)
                    oacc[dt][i] *= ci;
            }
        }

        // ---- P -> LDS, vectorized 8B writes (row q = l15) ----
        #pragma unroll
        for (int kt = 0; kt < 4; ++kt) {
            hf4 ph;
            #pragma unroll
            for (int r = 0; r < 4; ++r) ph[r] = (_Float16)s4[kt][r];
            *(hf4*)(P + l15 * 128 + ((kt * 32 + lg * 8) ^ rsw)) = ph;
        }
        asm volatile("s_waitcnt lgkmcnt(0)" ::: "memory");

        // ---- O += P V ----
        hf8 pa[2];
        pa[0] = *(const hf8*)(P + l15 * 128 + ((0  + lg * 16) ^ rsw));
        pa[1] = *(const hf8*)(P + l15 * 128 + ((64 + lg * 16) ^ rsw));
        #pragma unroll
        for (int dt = 0; dt < 4; ++dt) {
            f32x4 acc = oacc[dt];
            #pragma unroll
            for (int c = 0; c < 2; ++c) {
                const hf8 vb = *(const hf8*)(Vlds + (dt * 16 + l15) * 128 + ((c * 64 + lg * 16) ^ rsw));
                acc = __builtin_amdgcn_mfma_f32_16x16x32_f16(pa[c], vb, acc, 0, 0, 0);
            }
            oacc[dt] = acc;
        }
    }

    // ---- epilogue: normalized f16 partial + (m, l) ----
    const int Rbase = b * SEQ + qb + wid * 16;
    if (lg == 0)
        Ml[(size_t)(Rbase + l15) * SPLIT + seg] = make_float2(m, l);

    float inv[4];
    #pragma unroll
    for (int i = 0; i < 4; ++i)
        inv[i] = 1.0f / __shfl(l, lg * 4 + i, 64);
    #pragma unroll
    for (int dt = 0; dt < 4; ++dt)
        #pragma unroll
        for (int i = 0; i < 4; ++i) {
            const size_t R = (size_t)(Rbase + lg * 4 + i);
            Opart[(R * SPLIT + seg) * DIM + dt * 16 + l15] =
                (_Float16)(oacc[dt][i] * inv[i]);
        }
}

// ---------------------------------------------------------------------------
// Combine: O = sum_s (l_s * 2^(m_s - M) / W) * O_s
// ---------------------------------------------------------------------------
__global__ __launch_bounds__(256) void attn_combine(
    const _Float16* __restrict__ Opart, const float2* __restrict__ Ml,
    float* __restrict__ Og)
{
    const int gid = blockIdx.x * 256 + threadIdx.x;   // (R, d-octet)
    const int R   = gid >> 3;
    const int d0  = (gid & 7) * 8;

    const float2* mlp = Ml + (size_t)R * SPLIT;
    float mv[SPLIT], lv[SPLIT];
    float M = -INFINITY;
    #pragma unroll
    for (int s = 0; s < SPLIT; ++s) {
        const float2 ml = mlp[s];
        mv[s] = ml.x; lv[s] = ml.y;
        M = fmaxf(M, ml.x);
    }
    float w[SPLIT], W = 0.f;
    #pragma unroll
    for (int s = 0; s < SPLIT; ++s) { w[s] = lv[s] * exp2f(mv[s] - M); W += w[s]; }
    const float invW = 1.0f / W;

    float out[8] = {};
    #pragma unroll
    for (int s = 0; s < SPLIT; ++s) {
        const hf8 o = *(const hf8*)(Opart + ((size_t)R * SPLIT + s) * DIM + d0);
        const float ws = w[s] * invW;
        #pragma unroll
        for (int j = 0; j < 8; ++j) out[j] += ws * (float)o[j];
    }
    float4 o0 = {out[0], out[1], out[2], out[3]};
    float4 o1 = {out[4], out[5], out[6], out[7]};
    *(float4*)(Og + (size_t)R * DIM + d0)     = o0;
    *(float4*)(Og + (size_t)R * DIM + d0 + 4) = o1;
}

// ---------------------------------------------------------------------------
// Round-2 single-pass kernel (fallback if ws too small for split buffers)
// ---------------------------------------------------------------------------
__global__ __launch_bounds__(256) void attn_fwd_f16(
    const _Float16* __restrict__ Qh,
    const _Float16* __restrict__ Kh,
    const _Float16* __restrict__ Vth,
    float* __restrict__ Og)
{
    __shared__ int4 Klds4[512];
    __shared__ int4 Vlds4[512];
    __shared__ int4 Plds4[512];
    char* const Klds = (char*)Klds4;
    char* const Vlds = (char*)Vlds4;
    char* const Plds = (char*)Plds4;

    const int t    = threadIdx.x;
    const int lane = t & 63;
    const int wid  = t >> 6;
    const int l15  = lane & 15;
    const int lg   = lane >> 4;

    const int blk = blockIdx.x;
    const int b   = blk / (SEQ / QBLK);
    const int qb  = (blk % (SEQ / QBLK)) * QBLK;

    const _Float16* qrow = Qh + ((size_t)b * SEQ + qb + wid * 16 + l15) * DIM;
    hf8 qfrag[2];
    qfrag[0] = *(const hf8*)(qrow + lg * 8);
    qfrag[1] = *(const hf8*)(qrow + 32 + lg * 8);

    f32x4 oacc[4] = {};
    float m_i[4], l_i[4];
    #pragma unroll
    for (int i = 0; i < 4; ++i) { m_i[i] = -INFINITY; l_i[i] = 0.f; }

    const int sr = t >> 3;
    const int sc = (t & 7) * 8;
    const int swz = (sr & 7) << 4;
    const int boff0 = (sr)      * 128 + ((sc * 2) ^ swz);
    const int boff1 = (32 + sr) * 128 + ((sc * 2) ^ swz);

    const _Float16* Kbase = Kh  + (size_t)b * SEQ * DIM;
    const _Float16* Vbase = Vth + (size_t)b * DIM * SEQ;

    int4 pk0 = *(const int4*)(Kbase + (size_t)(sr)      * DIM + sc);
    int4 pk1 = *(const int4*)(Kbase + (size_t)(32 + sr) * DIM + sc);
    int4 pv0 = *(const int4*)(Vbase + (size_t)(sr)      * SEQ + sc);
    int4 pv1 = *(const int4*)(Vbase + (size_t)(32 + sr) * SEQ + sc);

    const int rsw = (l15 & 7) << 4;
    char* const P = Plds + wid * 2048;

    for (int kb = 0; kb < SEQ; kb += KBLK) {
        __syncthreads();
        *(int4*)(Klds + boff0) = pk0;
        *(int4*)(Klds + boff1) = pk1;
        *(int4*)(Vlds + boff0) = pv0;
        *(int4*)(Vlds + boff1) = pv1;
        __syncthreads();
        if (kb + KBLK < SEQ) {
            const int kn = kb + KBLK;
            pk0 = *(const int4*)(Kbase + (size_t)(kn + sr)      * DIM + sc);
            pk1 = *(const int4*)(Kbase + (size_t)(kn + 32 + sr) * DIM + sc);
            pv0 = *(const int4*)(Vbase + (size_t)(sr)      * SEQ + kn + sc);
            pv1 = *(const int4*)(Vbase + (size_t)(32 + sr) * SEQ + kn + sc);
        }

        f32x4 s[4];
        #pragma unroll
        for (int kt = 0; kt < 4; ++kt) {
            f32x4 acc = {};
            #pragma unroll
            for (int c = 0; c < 2; ++c) {
                const hf8 bf = *(const hf8*)(Klds + (kt * 16 + l15) * 128 + ((c * 64 + lg * 16) ^ rsw));
                acc = __builtin_amdgcn_mfma_f32_16x16x32_f16(qfrag[c], bf, acc, 0, 0, 0);
            }
            s[kt] = acc;
        }

        #pragma unroll
        for (int i = 0; i < 4; ++i) {
            float mx = fmaxf(fmaxf(s[0][i], s[1][i]), fmaxf(s[2][i], s[3][i]));
            #pragma unroll
            for (int mk = 1; mk <= 8; mk <<= 1)
                mx = fmaxf(mx, __shfl_xor(mx, mk, 64));
            const float mnew = fmaxf(m_i[i], mx);
            const float corr = __builtin_exp2f(m_i[i] - mnew);
            m_i[i] = mnew;

            float sum = 0.f;
            #pragma unroll
            for (int kt = 0; kt < 4; ++kt) {
                const float p = __builtin_exp2f(s[kt][i] - mnew);
                s[kt][i] = p;
                sum += p;
            }
            #pragma unroll
            for (int mk = 1; mk <= 8; mk <<= 1)
                sum += __shfl_xor(sum, mk, 64);
            l_i[i] = l_i[i] * corr + sum;

            #pragma unroll
            for (int dt = 0; dt < 4; ++dt)
                oacc[dt][i] *= corr;

            const int prow = lg * 4 + i;
            const int psw = (prow & 7) << 4;
            #pragma unroll
            for (int kt = 0; kt < 4; ++kt)
                *(_Float16*)(P + prow * 128 + (((kt * 16 + l15) * 2) ^ psw)) = (_Float16)s[kt][i];
        }
        asm volatile("s_waitcnt lgkmcnt(0)" ::: "memory");

        #pragma unroll
        for (int dt = 0; dt < 4; ++dt) {
            f32x4 acc = oacc[dt];
            #pragma unroll
            for (int c = 0; c < 2; ++c) {
                const hf8 pa = *(const hf8*)(P + l15 * 128 + ((c * 64 + lg * 16) ^ rsw));
                const hf8 vb = *(const hf8*)(Vlds + (dt * 16 + l15) * 128 + ((c * 64 + lg * 16) ^ rsw));
                acc = __builtin_amdgcn_mfma_f32_16x16x32_f16(pa, vb, acc, 0, 0, 0);
            }
            oacc[dt] = acc;
        }
    }

    float* orow = Og + ((size_t)b * SEQ + qb + wid * 16) * DIM;
    float inv[4];
    #pragma unroll
    for (int i = 0; i < 4; ++i) inv[i] = 1.0f / l_i[i];
    #pragma unroll
    for (int dt = 0; dt < 4; ++dt)
        #pragma unroll
        for (int i = 0; i < 4; ++i)
            orow[(size_t)(lg * 4 + i) * DIM + dt * 16 + l15] = oacc[dt][i] * inv[i];
}

extern "C" void kernel_launch(void* const* d_in, const int* in_sizes, int n_in,
                              void* d_out, int out_size, void* d_ws, size_t ws_size,
                              hipStream_t stream) {
    const float* Q = (const float*)d_in[0];
    const float* K = (const float*)d_in[1];
    const float* V = (const float*)d_in[2];
    float* O = (float*)d_out;
    const size_t nelem = (size_t)BATCH * SEQ * DIM;          // 2M
    const size_t pre_bytes   = nelem * 3 * sizeof(_Float16); // 12MB
    const size_t opart_bytes = nelem * SPLIT * sizeof(_Float16); // 16MB
    const size_t ml_bytes    = (size_t)BATCH * SEQ * SPLIT * sizeof(float2); // 1MB

    if (ws_size >= pre_bytes + opart_bytes + ml_bytes) {
        _Float16* Qh    = (_Float16*)d_ws;
        _Float16* Kh    = Qh + nelem;
        _Float16* Vth   = Kh + nelem;
        _Float16* Opart = Vth + nelem;
        float2*   Ml    = (float2*)((char*)d_ws + pre_bytes + opart_bytes);
        attn_preprocess<<<dim3(2560), dim3(256), 0, stream>>>(Q, K, V, Qh, Kh, Vth);
        attn_fwd_split<<<dim3(BATCH * (SEQ / QBLK) * SPLIT), dim3(256), 0, stream>>>(
            Qh, Kh, Vth, Opart, Ml);
        attn_combine<<<dim3((BATCH * SEQ * 8) / 256), dim3(256), 0, stream>>>(
            Opart, Ml, O);
    } else {
        _Float16* Qh  = (_Float16*)d_ws;
        _Float16* Kh  = Qh + nelem;
        _Float16* Vth = Kh + nelem;
        attn_preprocess<<<dim3(2560), dim3(256), 0, stream>>>(Q, K, V, Qh, Kh, Vth);
        attn_fwd_f16<<<dim3(BATCH * (SEQ / QBLK)), dim3(256), 0, stream>>>(Qh, Kh, Vth, O);
    }
}